// Round 10
// baseline (252.897 us; speedup 1.0000x reference)
//
#include <hip/hip_runtime.h>
#include <math.h>

// ---------------------------------------------------------------------------
// RotSSM: out[b,Do,t] = C2 @ scan(M @ u)[.,b,t] + D ⊙ u[b,.,t]
//   k0 (64 blocks): trace/expm/norm/Apow + M, C2 + ZERO the publish flags
//      (ws is re-poisoned by the harness each iteration).
//   k13 (128x8 blocks, LCH=32, regular launch): per block
//      Phase A: stage u -> MFMA GEMM1 -> local scan (z stays in LDS) ->
//               publish chunk total (release flag).
//      Wait:    per-thread acquire-poll on predecessor flags (publish
//               precedes wait on EVERY block -> deadlock-free; all 1024
//               blocks also fit resident: 4 waves, 16.9 KB LDS).
//      Phase B: carry = ascending Horner over published totals (<=127 FMAs)
//               -> correct z in LDS -> MFMA GEMM2 -> out + D⊙u.
//   vs round 8: Zst 33.6 MB HBM round-trip, k2+k3 dispatches, and k3's
//   reload phase all eliminated. Workspace ~1.35 MB.
// ---------------------------------------------------------------------------

typedef __attribute__((ext_vector_type(8))) short short8;   // 8 bf16 (4 VGPRs)
typedef __attribute__((ext_vector_type(4))) float f32x4;

#define TLEN 4096
#define LCH 32            // chunk length (t per block)
#define NCH 128           // number of chunks
#define BSZ 8
#define LDW 132           // dwords per [t] row (128 + 4 pad)
#define LDK 264           // shorts per [t] row (= LDW*2)

// workspace float offsets
constexpr int MB_OFF   = 0;                               // M bf16 [256][256]
constexpr int CB_OFF   = 32768;                           // C2 bf16 [256][256]
constexpr int AP_OFF   = 65536;                           // Apow [LCH+1][128] float2 (8448 f)
constexpr int FLG_OFF  = AP_OFF + (LCH + 1) * 256;        // flags [NCH][BSZ] u32 (1024)
constexpr int TOT_OFF  = FLG_OFF + NCH * BSZ;             // Tot [NCH][8][128] float2
// end = TOT_OFF + 262144 ~ 337K floats ~ 1.35 MB

__device__ __forceinline__ float bfbits2f(unsigned int bits16) {
  union { unsigned int u; float f; } v; v.u = bits16 << 16; return v.f;
}
__device__ __forceinline__ unsigned int f2bfbits(float f) {
  union { float f; unsigned int u; } v; v.f = f;
  return (v.u + 0x7fffu + ((v.u >> 16) & 1u)) >> 16;   // RNE, finite inputs
}
__device__ __forceinline__ unsigned int pack2(float x, float y) {
  return f2bfbits(x) | (f2bfbits(y) << 16);
}

// ---------------------------------------------------------------------------
// K0: one block per head. Zero flags; trace -> {expm | Apow | norm in
//     separate waves} -> M rows 4h..4h+3 and C2 cols 4h..4h+3.
// ---------------------------------------------------------------------------
__global__ __launch_bounds__(256) void k0_setup(
    const float* __restrict__ thetas_log, const float* __restrict__ P_param,
    const float* __restrict__ B_param, const float* __restrict__ C,
    const float* __restrict__ gamma_log, float* __restrict__ ws) {
  const int h = blockIdx.x;
  const int tid = threadIdx.x;
  __shared__ float red[4];
  __shared__ float Psh[16];
  __shared__ float nrmsh;

  // zero publish flags (ws is poisoned before every iteration)
  if (tid < 16) ((unsigned int*)(ws + FLG_OFF))[h * 16 + tid] = 0u;

  {
    float4 v = *(const float4*)(B_param + (size_t)h * 1024 + tid * 4);
    float s = v.x * v.x + v.y * v.y + v.z * v.z + v.w * v.w;
#pragma unroll
    for (int off = 32; off > 0; off >>= 1) s += __shfl_down(s, off);
    if ((tid & 63) == 0) red[tid >> 6] = s;
  }
  __syncthreads();

  if (tid == 0) {
    double A[4][4], E[4][4], Tm[4][4];
    for (int i = 0; i < 4; ++i)
      for (int j = 0; j < 4; ++j)
        A[i][j] = (double)P_param[h * 16 + i * 4 + j] - (double)P_param[h * 16 + j * 4 + i];
    double fro = 0.0;
    for (int i = 0; i < 4; ++i) for (int j = 0; j < 4; ++j) fro += A[i][j] * A[i][j];
    fro = sqrt(fro);
    int s = 0;
    while (fro > 0.25 && s < 30) { fro *= 0.5; ++s; }
    double scl = 1.0;
    for (int q2 = 0; q2 < s; ++q2) scl *= 0.5;
    for (int i = 0; i < 4; ++i) for (int j = 0; j < 4; ++j) A[i][j] *= scl;
    for (int i = 0; i < 4; ++i)
      for (int j = 0; j < 4; ++j) { E[i][j] = (i == j) ? 1.0 : 0.0; Tm[i][j] = E[i][j]; }
    for (int k = 1; k <= 16; ++k) {
      double Tn[4][4];
      for (int i = 0; i < 4; ++i)
        for (int j = 0; j < 4; ++j) {
          double acc = 0.0;
          for (int m = 0; m < 4; ++m) acc += Tm[i][m] * A[m][j];
          Tn[i][j] = acc / (double)k;
        }
      for (int i = 0; i < 4; ++i)
        for (int j = 0; j < 4; ++j) { Tm[i][j] = Tn[i][j]; E[i][j] += Tn[i][j]; }
    }
    for (int q2 = 0; q2 < s; ++q2) {
      double E2[4][4];
      for (int i = 0; i < 4; ++i)
        for (int j = 0; j < 4; ++j) {
          double acc = 0.0;
          for (int m = 0; m < 4; ++m) acc += E[i][m] * E[m][j];
          E2[i][j] = acc;
        }
      for (int i = 0; i < 4; ++i) for (int j = 0; j < 4; ++j) E[i][j] = E2[i][j];
    }
    for (int i = 0; i < 4; ++i)
      for (int j = 0; j < 4; ++j) Psh[i * 4 + j] = (float)E[i][j];
  } else if (tid == 64 || tid == 65) {
    const int p = h * 2 + (tid - 64);
    double th = exp((double)thetas_log[p]);
    double g = exp(-exp((double)gamma_log[h]));
    double ar = g * cos(th), ai = g * sin(th);
    float2* Apw = (float2*)(ws + AP_OFF);
    double xr = 1.0, xi = 0.0;
    Apw[p] = make_float2(1.f, 0.f);
    for (int j = 1; j <= LCH; ++j) {
      double nr = xr * ar - xi * ai, ni = xr * ai + xi * ar;
      xr = nr; xi = ni;
      Apw[j * 128 + p] = make_float2((float)xr, (float)xi);
    }
  } else if (tid == 128) {
    double g = exp(-exp((double)gamma_log[h]));
    double tr = (double)red[0] + red[1] + red[2] + red[3];
    nrmsh = (float)sqrt((1.0 - g * g) / tr);
  }
  __syncthreads();

  unsigned short* Mbf = (unsigned short*)(ws + MB_OFF);
  unsigned int*   Cbd = (unsigned int*)(ws + CB_OFF);
  {
    float b0 = B_param[(h * 4 + 0) * 256 + tid];
    float b1 = B_param[(h * 4 + 1) * 256 + tid];
    float b2 = B_param[(h * 4 + 2) * 256 + tid];
    float b3 = B_param[(h * 4 + 3) * 256 + tid];
    float nrm = nrmsh;
#pragma unroll
    for (int N = 0; N < 4; ++N) {
      float acc = Psh[N * 4 + 0] * b0 + Psh[N * 4 + 1] * b1 +
                  Psh[N * 4 + 2] * b2 + Psh[N * 4 + 3] * b3;
      Mbf[(h * 4 + N) * 256 + tid] = (unsigned short)f2bfbits(nrm * acc);
    }
  }
  {
    float4 cv = *(const float4*)(C + (size_t)tid * 256 + h * 4);
    float o[4];
#pragma unroll
    for (int N = 0; N < 4; ++N)
      o[N] = cv.x * Psh[N * 4 + 0] + cv.y * Psh[N * 4 + 1] +
             cv.z * Psh[N * 4 + 2] + cv.w * Psh[N * 4 + 3];
    Cbd[(tid * 256 + h * 4) >> 1]       = pack2(o[0], o[1]);
    Cbd[((tid * 256 + h * 4) >> 1) + 1] = pack2(o[2], o[3]);
  }
}

// ---------------------------------------------------------------------------
// K13: fused phase A -> publish -> acquire-poll -> Horner carry -> correct
//      -> GEMM2 -> epilogue. z never leaves LDS.
// ---------------------------------------------------------------------------
__global__ __launch_bounds__(256, 4) void k13_fused(
    const float* __restrict__ u, const float* __restrict__ Dv,
    float* __restrict__ ws, float* __restrict__ out) {
  __shared__ __align__(16) unsigned char smem[LCH * LDK * 2];   // 16896 B
  unsigned short* us = (unsigned short*)smem;   // u tile [t][LDK] shorts
  unsigned int*   wd = (unsigned int*)smem;     // same, as [t][LDW] dwords

  const int c = blockIdx.x, b = blockIdx.y;
  const int t0 = c * LCH;
  const int tid = threadIdx.x;
  const int L = tid & 63;
  const int w = __builtin_amdgcn_readfirstlane(tid >> 6);
  const int qh = L >> 4, l15 = L & 15;
  unsigned int* flg = (unsigned int*)(ws + FLG_OFF);

  // ---- Phase A: stage u[d][t0+t] -> wd[t][j] (j = d/2, pair-packed) ----
  {
    const int dp = tid >> 3;                // 0..31
    const int t4 = (tid & 7) * 4;           // 0..28
#pragma unroll
    for (int i = 0; i < 4; ++i) {
      int j = dp + 32 * i;                  // pair index 0..127
      float4 va = *(const float4*)(u + (size_t)(b * 256 + 2 * j) * TLEN + t0 + t4);
      float4 vb = *(const float4*)(u + (size_t)(b * 256 + 2 * j + 1) * TLEN + t0 + t4);
      float av[4] = {va.x, va.y, va.z, va.w};
      float bv[4] = {vb.x, vb.y, vb.z, vb.w};
#pragma unroll
      for (int dt = 0; dt < 4; ++dt)
        wd[(t4 + dt) * LDW + j] = pack2(av[dt], bv[dt]);
    }
  }
  __syncthreads();

  // ---- GEMM1: W[256][32] = M @ u_tile ----
  f32x4 acc[4][2];
#pragma unroll
  for (int rt = 0; rt < 4; ++rt)
#pragma unroll
    for (int tt = 0; tt < 2; ++tt) acc[rt][tt] = (f32x4){0.f, 0.f, 0.f, 0.f};
  {
    const unsigned short* Mbf = (const unsigned short*)(ws + MB_OFF);
#pragma unroll
    for (int ks = 0; ks < 8; ++ks) {
      short8 af[4], bf[2];
#pragma unroll
      for (int rt = 0; rt < 4; ++rt)
        af[rt] = *(const short8*)(Mbf + (size_t)(w * 64 + rt * 16 + l15) * 256 + ks * 32 + qh * 8);
#pragma unroll
      for (int tt = 0; tt < 2; ++tt)
        bf[tt] = *(const short8*)(us + (tt * 16 + l15) * LDK + ks * 32 + qh * 8);
#pragma unroll
      for (int rt = 0; rt < 4; ++rt)
#pragma unroll
        for (int tt = 0; tt < 2; ++tt)
          acc[rt][tt] = __builtin_amdgcn_mfma_f32_16x16x32_bf16(af[rt], bf[tt], acc[rt][tt], 0, 0, 0);
    }
  }
  __syncthreads();   // all us reads done before overwrite (alias)

  // ---- W -> wd[t][p] pair-packed bf16 (D: row=qh*4+q, col=l15) ----
#pragma unroll
  for (int rt = 0; rt < 4; ++rt) {
    int pbase = w * 32 + rt * 8 + qh * 2;   // dword index = state-row/2
#pragma unroll
    for (int tt = 0; tt < 2; ++tt) {
      int t = tt * 16 + l15;
      f32x4 a4 = acc[rt][tt];
      wd[t * LDW + pbase]     = pack2(a4[0], a4[1]);
      wd[t * LDW + pbase + 1] = pack2(a4[2], a4[3]);
    }
  }
  __syncthreads();

  // ---- local scan (fp32 state, bf16 in LDS), publish chunk total ----
  if (tid < 128) {
    const int p = tid;
    const float2* Apw = (const float2*)(ws + AP_OFF);
    float2 a = Apw[128 + p];       // a^1
    float zr = 0.f, zi = 0.f;
#pragma unroll
    for (int t = 0; t < LCH; ++t) {
      unsigned int wv = wd[t * LDW + p];
      float wr = bfbits2f(wv & 0xffffu), wi = bfbits2f(wv >> 16);
      float nr = fmaf(a.x, zr, fmaf(-a.y, zi, wr));
      float ni = fmaf(a.x, zi, fmaf(a.y, zr, wi));
      zr = nr; zi = ni;
      wd[t * LDW + p] = pack2(zr, zi);
    }
    ((float2*)(ws + TOT_OFF))[(c * BSZ + b) * 128 + p] = make_float2(zr, zi);
  }
  __syncthreads();                 // all Tot stores drained (vmcnt) pre-flag
  if (tid == 0) {
    __threadfence();               // device-scope visibility of Tot
    __hip_atomic_store(&flg[c * BSZ + b], 1u, __ATOMIC_RELEASE,
                       __HIP_MEMORY_SCOPE_AGENT);
  }

  // ---- acquire-poll: every Tot-reading thread acquires a flag ----
  if (c > 0) {
    const int p = tid & 127;
    const int cp = (p < c) ? p : (c - 1);  // covers all cp<c across threads
    while (__hip_atomic_load(&flg[cp * BSZ + b], __ATOMIC_ACQUIRE,
                             __HIP_MEMORY_SCOPE_AGENT) == 0u)
      __builtin_amdgcn_s_sleep(2);
  }
  __syncthreads();

  // ---- Phase B: Horner carry over totals + correct z (t-split, 256 thr) ----
  if (c > 0) {
    const int p = tid & 127;
    const int thalf = (tid >> 7) * 16;     // 0-127: t 0..15; 128-255: t 16..31
    const float2* Tot = (const float2*)(ws + TOT_OFF);
    const float2* Apw = (const float2*)(ws + AP_OFF);
    const float2 aL = Apw[LCH * 128 + p];  // a^LCH
    float cr = 0.f, ci = 0.f;
    // carry entering chunk c: S = sum_{cp<c} aL^{c-1-cp} Tot_cp  (ascending Horner)
#pragma unroll 4
    for (int cp = 0; cp < c; ++cp) {
      float2 tv = Tot[(size_t)(cp * BSZ + b) * 128 + p];
      float nr = fmaf(aL.x, cr, fmaf(-aL.y, ci, tv.x));
      float ni = fmaf(aL.x, ci, fmaf(aL.y, cr, tv.y));
      cr = nr; ci = ni;
    }
#pragma unroll
    for (int tt2 = 0; tt2 < 16; ++tt2) {
      int t = thalf + tt2;
      unsigned int wv = wd[t * LDW + p];
      float2 ap = Apw[(t + 1) * 128 + p];
      float sr = fmaf(ap.x, cr, fmaf(-ap.y, ci, bfbits2f(wv & 0xffffu)));
      float si = fmaf(ap.x, ci, fmaf(ap.y, cr, bfbits2f(wv >> 16)));
      wd[t * LDW + p] = pack2(sr, si);
    }
  }
  __syncthreads();

  // ---- GEMM2: out_tile = C2 @ Z ----
  f32x4 acc2[4][2];
#pragma unroll
  for (int rt = 0; rt < 4; ++rt)
#pragma unroll
    for (int tt = 0; tt < 2; ++tt) acc2[rt][tt] = (f32x4){0.f, 0.f, 0.f, 0.f};
  {
    const unsigned short* Cbf = (const unsigned short*)(ws + CB_OFF);
    const unsigned short* zs  = (const unsigned short*)smem;
#pragma unroll
    for (int ks = 0; ks < 8; ++ks) {
      short8 af[4], bf[2];
#pragma unroll
      for (int rt = 0; rt < 4; ++rt)
        af[rt] = *(const short8*)(Cbf + (size_t)(w * 64 + rt * 16 + l15) * 256 + ks * 32 + qh * 8);
#pragma unroll
      for (int tt = 0; tt < 2; ++tt)
        bf[tt] = *(const short8*)(zs + (tt * 16 + l15) * LDK + ks * 32 + qh * 8);
#pragma unroll
      for (int rt = 0; rt < 4; ++rt)
#pragma unroll
        for (int tt = 0; tt < 2; ++tt)
          acc2[rt][tt] = __builtin_amdgcn_mfma_f32_16x16x32_bf16(af[rt], bf[tt], acc2[rt][tt], 0, 0, 0);
    }
  }

  // ---- epilogue: out = acc2 + D ⊙ u ----
  float dv[4][4];
#pragma unroll
  for (int rt = 0; rt < 4; ++rt)
#pragma unroll
    for (int q = 0; q < 4; ++q) dv[rt][q] = Dv[w * 64 + rt * 16 + qh * 4 + q];
#pragma unroll
  for (int rt = 0; rt < 4; ++rt) {
    int Dbase = w * 64 + rt * 16 + qh * 4;
#pragma unroll
    for (int tt = 0; tt < 2; ++tt) {
      int t = tt * 16 + l15;
      f32x4 a4 = acc2[rt][tt];
      size_t obase = (size_t)(b * 256 + Dbase) * TLEN + t0 + t;
#pragma unroll
      for (int q = 0; q < 4; ++q)
        out[obase + (size_t)q * TLEN] = a4[q] + dv[rt][q] * u[obase + (size_t)q * TLEN];
    }
  }
}

extern "C" void kernel_launch(void* const* d_in, const int* in_sizes, int n_in,
                              void* d_out, int out_size, void* d_ws, size_t ws_size,
                              hipStream_t stream) {
  const float* u          = (const float*)d_in[0];
  const float* thetas_log = (const float*)d_in[1];
  const float* P_param    = (const float*)d_in[2];
  const float* B_param    = (const float*)d_in[3];
  const float* C          = (const float*)d_in[4];
  const float* Dvec       = (const float*)d_in[5];
  const float* gamma_log  = (const float*)d_in[6];
  float* out = (float*)d_out;
  float* ws  = (float*)d_ws;

  hipLaunchKernelGGL(k0_setup, dim3(64), dim3(256), 0, stream,
                     thetas_log, P_param, B_param, C, gamma_log, ws);
  hipLaunchKernelGGL(k13_fused, dim3(NCH, BSZ), dim3(256), 0, stream,
                     u, Dvec, ws, out);
}

// Round 12
// 225.580 us; speedup vs baseline: 1.1211x; 1.1211x over previous
//
#include <hip/hip_runtime.h>
#include <math.h>

// ---------------------------------------------------------------------------
// RotSSM: out[b,Do,t] = C2 @ scan(M @ u)[.,b,t] + D ⊙ u[b,.,t]
//   k0 (64 blocks): zero arrival counters; trace/expm/norm/Apow + M, C2.
//   k1 (128x8 blocks, LCH=32): stage u (nt loads) -> MFMA GEMM1 -> local
//      scan -> Zst direct + chunk totals. LAST block per batch b (atomic
//      arrival counter, ACQ_REL agent scope — pattern proven correct in
//      round 10) runs the exclusive Tot scan in-kernel (was k2).
//      LDS de-aliased (us 16.9K + wd 16.9K = 33.8K, 4 blocks/CU): one
//      fewer barrier, pack overlaps MFMA.
//   k3 (128x8 blocks): carry = one float2 load; fused reload+correct ->
//      LDS z tile -> MFMA GEMM2 -> out (nt stores) + D⊙u (nt loads).
//   Nontemporal on streamed-once u/out preserves L2 for Zst/M/Tot
//   (k1/k3 same block->XCD mapping => Zst reload can be L2-hot).
// ---------------------------------------------------------------------------

typedef __attribute__((ext_vector_type(8))) short short8;   // 8 bf16 (4 VGPRs)
typedef __attribute__((ext_vector_type(4))) float f32x4;

#define TLEN 4096
#define LCH 32            // chunk length (t per block)
#define NCH 128           // number of chunks
#define BSZ 8
#define LDW 132           // dwords per [t] row (128 + 4 pad)
#define LDK 264           // shorts per [t] row (= LDW*2)

// workspace float offsets (round-8 proven layout; CNT lives in dead ALP area)
constexpr int MB_OFF   = 0;                               // M bf16 [256][256]
constexpr int CB_OFF   = 32768;                           // C2 bf16 [256][256]
constexpr int AP_OFF   = 65536;                           // Apow [LCH+1][128] float2
constexpr int CNT_OFF  = AP_OFF + (LCH + 1) * 256;        // arrival counters [BSZ] u32
constexpr int TOT_OFF  = CNT_OFF + (NCH + 1) * 256;       // Tot/Carry [NCH][8][128] float2
constexpr int ZST_OFF  = TOT_OFF + NCH * BSZ * 256;       // Zst [NCH*8][4096] dwords

__device__ __forceinline__ float bfbits2f(unsigned int bits16) {
  union { unsigned int u; float f; } v; v.u = bits16 << 16; return v.f;
}
__device__ __forceinline__ unsigned int f2bfbits(float f) {
  union { float f; unsigned int u; } v; v.f = f;
  return (v.u + 0x7fffu + ((v.u >> 16) & 1u)) >> 16;   // RNE, finite inputs
}
__device__ __forceinline__ unsigned int pack2(float x, float y) {
  return f2bfbits(x) | (f2bfbits(y) << 16);
}

// ---------------------------------------------------------------------------
// K0: one block per head. Zero counters; trace -> {expm | Apow | norm in
//     separate waves} -> M rows 4h..4h+3 and C2 cols 4h..4h+3.
// ---------------------------------------------------------------------------
__global__ __launch_bounds__(256) void k0_setup(
    const float* __restrict__ thetas_log, const float* __restrict__ P_param,
    const float* __restrict__ B_param, const float* __restrict__ C,
    const float* __restrict__ gamma_log, float* __restrict__ ws) {
  const int h = blockIdx.x;
  const int tid = threadIdx.x;
  __shared__ float red[4];
  __shared__ float Psh[16];
  __shared__ float nrmsh;

  // zero arrival counters (ws is poisoned before every iteration)
  if (h == 0 && tid < BSZ) ((unsigned int*)(ws + CNT_OFF))[tid] = 0u;

  {
    float4 v = *(const float4*)(B_param + (size_t)h * 1024 + tid * 4);
    float s = v.x * v.x + v.y * v.y + v.z * v.z + v.w * v.w;
#pragma unroll
    for (int off = 32; off > 0; off >>= 1) s += __shfl_down(s, off);
    if ((tid & 63) == 0) red[tid >> 6] = s;
  }
  __syncthreads();

  if (tid == 0) {
    double A[4][4], E[4][4], Tm[4][4];
    for (int i = 0; i < 4; ++i)
      for (int j = 0; j < 4; ++j)
        A[i][j] = (double)P_param[h * 16 + i * 4 + j] - (double)P_param[h * 16 + j * 4 + i];
    double fro = 0.0;
    for (int i = 0; i < 4; ++i) for (int j = 0; j < 4; ++j) fro += A[i][j] * A[i][j];
    fro = sqrt(fro);
    int s = 0;
    while (fro > 0.25 && s < 30) { fro *= 0.5; ++s; }
    double scl = 1.0;
    for (int q2 = 0; q2 < s; ++q2) scl *= 0.5;
    for (int i = 0; i < 4; ++i) for (int j = 0; j < 4; ++j) A[i][j] *= scl;
    for (int i = 0; i < 4; ++i)
      for (int j = 0; j < 4; ++j) { E[i][j] = (i == j) ? 1.0 : 0.0; Tm[i][j] = E[i][j]; }
    for (int k = 1; k <= 16; ++k) {
      double Tn[4][4];
      for (int i = 0; i < 4; ++i)
        for (int j = 0; j < 4; ++j) {
          double acc = 0.0;
          for (int m = 0; m < 4; ++m) acc += Tm[i][m] * A[m][j];
          Tn[i][j] = acc / (double)k;
        }
      for (int i = 0; i < 4; ++i)
        for (int j = 0; j < 4; ++j) { Tm[i][j] = Tn[i][j]; E[i][j] += Tn[i][j]; }
    }
    for (int q2 = 0; q2 < s; ++q2) {
      double E2[4][4];
      for (int i = 0; i < 4; ++i)
        for (int j = 0; j < 4; ++j) {
          double acc = 0.0;
          for (int m = 0; m < 4; ++m) acc += E[i][m] * E[m][j];
          E2[i][j] = acc;
        }
      for (int i = 0; i < 4; ++i) for (int j = 0; j < 4; ++j) E[i][j] = E2[i][j];
    }
    for (int i = 0; i < 4; ++i)
      for (int j = 0; j < 4; ++j) Psh[i * 4 + j] = (float)E[i][j];
  } else if (tid == 64 || tid == 65) {
    const int p = h * 2 + (tid - 64);
    double th = exp((double)thetas_log[p]);
    double g = exp(-exp((double)gamma_log[h]));
    double ar = g * cos(th), ai = g * sin(th);
    float2* Apw = (float2*)(ws + AP_OFF);
    double xr = 1.0, xi = 0.0;
    Apw[p] = make_float2(1.f, 0.f);
    for (int j = 1; j <= LCH; ++j) {
      double nr = xr * ar - xi * ai, ni = xr * ai + xi * ar;
      xr = nr; xi = ni;
      Apw[j * 128 + p] = make_float2((float)xr, (float)xi);
    }
  } else if (tid == 128) {
    double g = exp(-exp((double)gamma_log[h]));
    double tr = (double)red[0] + red[1] + red[2] + red[3];
    nrmsh = (float)sqrt((1.0 - g * g) / tr);
  }
  __syncthreads();

  unsigned short* Mbf = (unsigned short*)(ws + MB_OFF);
  unsigned int*   Cbd = (unsigned int*)(ws + CB_OFF);
  {
    float b0 = B_param[(h * 4 + 0) * 256 + tid];
    float b1 = B_param[(h * 4 + 1) * 256 + tid];
    float b2 = B_param[(h * 4 + 2) * 256 + tid];
    float b3 = B_param[(h * 4 + 3) * 256 + tid];
    float nrm = nrmsh;
#pragma unroll
    for (int N = 0; N < 4; ++N) {
      float acc = Psh[N * 4 + 0] * b0 + Psh[N * 4 + 1] * b1 +
                  Psh[N * 4 + 2] * b2 + Psh[N * 4 + 3] * b3;
      Mbf[(h * 4 + N) * 256 + tid] = (unsigned short)f2bfbits(nrm * acc);
    }
  }
  {
    float4 cv = *(const float4*)(C + (size_t)tid * 256 + h * 4);
    float o[4];
#pragma unroll
    for (int N = 0; N < 4; ++N)
      o[N] = cv.x * Psh[N * 4 + 0] + cv.y * Psh[N * 4 + 1] +
             cv.z * Psh[N * 4 + 2] + cv.w * Psh[N * 4 + 3];
    Cbd[(tid * 256 + h * 4) >> 1]       = pack2(o[0], o[1]);
    Cbd[((tid * 256 + h * 4) >> 1) + 1] = pack2(o[2], o[3]);
  }
}

// ---------------------------------------------------------------------------
// K1: stage u (nt) -> GEMM1 -> scan (direct Zst) -> totals; last block per
//     batch runs the Tot exclusive scan (merged k2). De-aliased LDS.
// ---------------------------------------------------------------------------
__global__ __launch_bounds__(256, 4) void k1_mfma(
    const float* __restrict__ u, float* __restrict__ ws) {
  __shared__ __align__(16) unsigned short us[LCH * LDK];   // u tile, 16896 B
  __shared__ __align__(16) unsigned int   wd[LCH * LDW];   // W tile,  16896 B
  __shared__ unsigned int lastsh;

  const int c = blockIdx.x, b = blockIdx.y;
  const int t0 = c * LCH;
  const int tid = threadIdx.x;
  const int L = tid & 63;
  const int w = __builtin_amdgcn_readfirstlane(tid >> 6);
  const int qh = L >> 4, l15 = L & 15;

  // ---- stage u[d][t0+t] -> us[t][j] (j = d/2, pair-packed dwords) ----
  {
    unsigned int* usd = (unsigned int*)us;
    const int dp = tid >> 3;                // 0..31
    const int t4 = (tid & 7) * 4;           // 0..28
#pragma unroll
    for (int i = 0; i < 4; ++i) {
      int j = dp + 32 * i;                  // pair index 0..127
      f32x4 va = __builtin_nontemporal_load(
          (const f32x4*)(u + (size_t)(b * 256 + 2 * j) * TLEN + t0 + t4));
      f32x4 vb = __builtin_nontemporal_load(
          (const f32x4*)(u + (size_t)(b * 256 + 2 * j + 1) * TLEN + t0 + t4));
#pragma unroll
      for (int dt = 0; dt < 4; ++dt)
        usd[(t4 + dt) * LDW + j] = pack2(va[dt], vb[dt]);
    }
  }
  __syncthreads();

  // ---- GEMM1: W[256][32] = M @ u_tile ----
  f32x4 acc[4][2];
#pragma unroll
  for (int rt = 0; rt < 4; ++rt)
#pragma unroll
    for (int tt = 0; tt < 2; ++tt) acc[rt][tt] = (f32x4){0.f, 0.f, 0.f, 0.f};
  {
    const unsigned short* Mbf = (const unsigned short*)(ws + MB_OFF);
#pragma unroll
    for (int ks = 0; ks < 8; ++ks) {
      short8 af[4], bf[2];
#pragma unroll
      for (int rt = 0; rt < 4; ++rt)
        af[rt] = *(const short8*)(Mbf + (size_t)(w * 64 + rt * 16 + l15) * 256 + ks * 32 + qh * 8);
#pragma unroll
      for (int tt = 0; tt < 2; ++tt)
        bf[tt] = *(const short8*)(us + (tt * 16 + l15) * LDK + ks * 32 + qh * 8);
#pragma unroll
      for (int rt = 0; rt < 4; ++rt)
#pragma unroll
        for (int tt = 0; tt < 2; ++tt)
          acc[rt][tt] = __builtin_amdgcn_mfma_f32_16x16x32_bf16(af[rt], bf[tt], acc[rt][tt], 0, 0, 0);
    }
  }
  // no barrier needed: wd is a separate buffer, each wave packs its own acc

  // ---- W -> wd[t][p] pair-packed bf16 (D: row=qh*4+q, col=l15) ----
#pragma unroll
  for (int rt = 0; rt < 4; ++rt) {
    int pbase = w * 32 + rt * 8 + qh * 2;   // dword index = state-row/2
#pragma unroll
    for (int tt = 0; tt < 2; ++tt) {
      int t = tt * 16 + l15;
      f32x4 a4 = acc[rt][tt];
      wd[t * LDW + pbase]     = pack2(a4[0], a4[1]);
      wd[t * LDW + pbase + 1] = pack2(a4[2], a4[3]);
    }
  }
  __syncthreads();

  // ---- local scan (fp32 state), z -> Zst DIRECT (coalesced), totals ----
  if (tid < 128) {
    const int p = tid;
    const float2* Apw = (const float2*)(ws + AP_OFF);
    unsigned int* Zg = (unsigned int*)(ws + ZST_OFF) + (size_t)(c * BSZ + b) * 4096;
    float2 a = Apw[128 + p];       // a^1
    float zr = 0.f, zi = 0.f;
#pragma unroll
    for (int t = 0; t < LCH; ++t) {
      unsigned int wv = wd[t * LDW + p];
      float wr = bfbits2f(wv & 0xffffu), wi = bfbits2f(wv >> 16);
      float nr = fmaf(a.x, zr, fmaf(-a.y, zi, wr));
      float ni = fmaf(a.x, zi, fmaf(a.y, zr, wi));
      zr = nr; zi = ni;
      Zg[t * 128 + p] = pack2(zr, zi);     // 128 thr x 4B = 512B coalesced
    }
    ((float2*)(ws + TOT_OFF))[(c * BSZ + b) * 128 + p] = make_float2(zr, zi);
  }
  __syncthreads();   // drains all Tot/Zst stores (vmcnt 0 at barrier)

  // ---- arrival: last block for batch b runs the Tot exclusive scan ----
  if (tid == 0) {
    __threadfence();
    unsigned int prev = __hip_atomic_fetch_add(
        (unsigned int*)(ws + CNT_OFF) + b, 1u,
        __ATOMIC_ACQ_REL, __HIP_MEMORY_SCOPE_AGENT);
    lastsh = (prev == NCH - 1) ? 1u : 0u;
  }
  __syncthreads();
  if (lastsh && tid < 128) {
    const int p = tid;
    const float2* Apw = (const float2*)(ws + AP_OFF);
    float2* Tot = (float2*)(ws + TOT_OFF);
    const float2 aL = Apw[LCH * 128 + p];   // a^LCH
    float cr = 0.f, ci = 0.f;
    for (int c0 = 0; c0 < NCH; c0 += 16) {
      float2 tv[16];
#pragma unroll
      for (int k = 0; k < 16; ++k)
        tv[k] = Tot[(size_t)((c0 + k) * BSZ + b) * 128 + p];  // 16 in flight
#pragma unroll
      for (int k = 0; k < 16; ++k) {
        Tot[(size_t)((c0 + k) * BSZ + b) * 128 + p] = make_float2(cr, ci);
        float nr = fmaf(aL.x, cr, fmaf(-aL.y, ci, tv[k].x));
        float ni = fmaf(aL.x, ci, fmaf(aL.y, cr, tv[k].y));
        cr = nr; ci = ni;
      }
    }
  }
}

// ---------------------------------------------------------------------------
// K3: carry = one float2 load; fused reload+correct -> LDS z tile ->
//     MFMA GEMM2 -> out (nt) + D⊙u (nt).
// ---------------------------------------------------------------------------
__global__ __launch_bounds__(256, 4) void k3_mfma(
    const float* __restrict__ u, const float* __restrict__ Dv,
    const float* __restrict__ ws, float* __restrict__ out) {
  __shared__ __align__(16) unsigned char smem[LCH * LDK * 2];
  unsigned int* wd = (unsigned int*)smem;       // z tile [t][LDW] dwords

  const int c = blockIdx.x, b = blockIdx.y;
  const int t0 = c * LCH;
  const int tid = threadIdx.x;
  const int L = tid & 63;
  const int w = __builtin_amdgcn_readfirstlane(tid >> 6);
  const int qh = L >> 4, l15 = L & 15;

  // ---- fused reload + carry-correct (p constant per thread) ----
  {
    const int p = tid & 127;
    const float2 cv = ((const float2*)(ws + TOT_OFF))[(size_t)(c * BSZ + b) * 128 + p];
    const float2* Apw = (const float2*)(ws + AP_OFF);
    const unsigned int* Zg = (const unsigned int*)(ws + ZST_OFF) + (size_t)(c * BSZ + b) * 4096;
#pragma unroll
    for (int jj = 0; jj < 16; ++jj) {
      int idx = tid + 256 * jj;
      int t = idx >> 7;
      unsigned int wv = Zg[idx];
      float2 ap = Apw[(t + 1) * 128 + p];
      float sr = fmaf(ap.x, cv.x, fmaf(-ap.y, cv.y, bfbits2f(wv & 0xffffu)));
      float si = fmaf(ap.x, cv.y, fmaf(ap.y, cv.x, bfbits2f(wv >> 16)));
      wd[t * LDW + p] = pack2(sr, si);
    }
  }
  __syncthreads();

  // ---- GEMM2: out_tile = C2 @ Z ----
  f32x4 acc[4][2];
#pragma unroll
  for (int rt = 0; rt < 4; ++rt)
#pragma unroll
    for (int tt = 0; tt < 2; ++tt) acc[rt][tt] = (f32x4){0.f, 0.f, 0.f, 0.f};
  {
    const unsigned short* Cbf = (const unsigned short*)(ws + CB_OFF);
    const unsigned short* zs  = (const unsigned short*)smem;
#pragma unroll
    for (int ks = 0; ks < 8; ++ks) {
      short8 af[4], bf[2];
#pragma unroll
      for (int rt = 0; rt < 4; ++rt)
        af[rt] = *(const short8*)(Cbf + (size_t)(w * 64 + rt * 16 + l15) * 256 + ks * 32 + qh * 8);
#pragma unroll
      for (int tt = 0; tt < 2; ++tt)
        bf[tt] = *(const short8*)(zs + (tt * 16 + l15) * LDK + ks * 32 + qh * 8);
#pragma unroll
      for (int rt = 0; rt < 4; ++rt)
#pragma unroll
        for (int tt = 0; tt < 2; ++tt)
          acc[rt][tt] = __builtin_amdgcn_mfma_f32_16x16x32_bf16(af[rt], bf[tt], acc[rt][tt], 0, 0, 0);
    }
  }

  // ---- epilogue: out = acc + D ⊙ u (nontemporal streams) ----
  float dv[4][4];
#pragma unroll
  for (int rt = 0; rt < 4; ++rt)
#pragma unroll
    for (int q = 0; q < 4; ++q) dv[rt][q] = Dv[w * 64 + rt * 16 + qh * 4 + q];
#pragma unroll
  for (int rt = 0; rt < 4; ++rt) {
    int Dbase = w * 64 + rt * 16 + qh * 4;
#pragma unroll
    for (int tt = 0; tt < 2; ++tt) {
      int t = tt * 16 + l15;
      f32x4 a4 = acc[rt][tt];
      size_t obase = (size_t)(b * 256 + Dbase) * TLEN + t0 + t;
#pragma unroll
      for (int q = 0; q < 4; ++q) {
        float uv = __builtin_nontemporal_load(u + obase + (size_t)q * TLEN);
        __builtin_nontemporal_store(a4[q] + dv[rt][q] * uv,
                                    out + obase + (size_t)q * TLEN);
      }
    }
  }
}

extern "C" void kernel_launch(void* const* d_in, const int* in_sizes, int n_in,
                              void* d_out, int out_size, void* d_ws, size_t ws_size,
                              hipStream_t stream) {
  const float* u          = (const float*)d_in[0];
  const float* thetas_log = (const float*)d_in[1];
  const float* P_param    = (const float*)d_in[2];
  const float* B_param    = (const float*)d_in[3];
  const float* C          = (const float*)d_in[4];
  const float* Dvec       = (const float*)d_in[5];
  const float* gamma_log  = (const float*)d_in[6];
  float* out = (float*)d_out;
  float* ws  = (float*)d_ws;

  hipLaunchKernelGGL(k0_setup, dim3(64), dim3(256), 0, stream,
                     thetas_log, P_param, B_param, C, gamma_log, ws);
  hipLaunchKernelGGL(k1_mfma, dim3(NCH, BSZ), dim3(256), 0, stream, u, ws);
  hipLaunchKernelGGL(k3_mfma, dim3(NCH, BSZ), dim3(256), 0, stream, u, Dvec, ws, out);
}

// Round 13
// 157.289 us; speedup vs baseline: 1.6079x; 1.4342x over previous
//
#include <hip/hip_runtime.h>
#include <math.h>

// ---------------------------------------------------------------------------
// RotSSM: out[b,Do,t] = C2 @ scan(M @ u)[.,b,t] + D ⊙ u[b,.,t]
//   Round-8 proven structure (157.4 µs) + ONE delta: k1 LDS de-aliased
//   (us/wd separate buffers -> GEMM1->pack barrier removed; pack is
//   intra-thread so no sync needed). No nontemporal, no atomics (round-12
//   post-mortem: nt bypassed warm L3; per-block agent fence = L2 flush).
//   k0 (64 blocks): trace/expm/norm/Apow + M, C2.
//   k1 (128x8): stage u -> MFMA GEMM1 -> scan -> Zst direct + totals.
//   k2 (8x128): exclusive Tot scan over chunks, 16-deep prefetch.
//   k3 (128x8): carry = one float2 load; reload+correct -> GEMM2 -> out.
// ---------------------------------------------------------------------------

typedef __attribute__((ext_vector_type(8))) short short8;   // 8 bf16 (4 VGPRs)
typedef __attribute__((ext_vector_type(4))) float f32x4;

#define TLEN 4096
#define LCH 32            // chunk length (t per block)
#define NCH 128           // number of chunks
#define BSZ 8
#define LDW 132           // dwords per [t] row (128 + 4 pad)
#define LDK 264           // shorts per [t] row (= LDW*2)

// workspace float offsets (round-8 proven layout)
constexpr int MB_OFF   = 0;                               // M bf16 [256][256]
constexpr int CB_OFF   = 32768;                           // C2 bf16 [256][256]
constexpr int AP_OFF   = 65536;                           // Apow [LCH+1][128] float2
constexpr int ALP_OFF  = AP_OFF + (LCH + 1) * 256;        // (unused, layout keep)
constexpr int TOT_OFF  = ALP_OFF + (NCH + 1) * 256;       // Tot/Carry [NCH][8][128] float2
constexpr int ZST_OFF  = TOT_OFF + NCH * BSZ * 256;       // Zst [NCH*8][4096] dwords

__device__ __forceinline__ float bfbits2f(unsigned int bits16) {
  union { unsigned int u; float f; } v; v.u = bits16 << 16; return v.f;
}
__device__ __forceinline__ unsigned int f2bfbits(float f) {
  union { float f; unsigned int u; } v; v.f = f;
  return (v.u + 0x7fffu + ((v.u >> 16) & 1u)) >> 16;   // RNE, finite inputs
}
__device__ __forceinline__ unsigned int pack2(float x, float y) {
  return f2bfbits(x) | (f2bfbits(y) << 16);
}

// ---------------------------------------------------------------------------
// K0: one block per head. trace -> {expm | Apow | norm, separate waves}
//     -> M rows 4h..4h+3 and C2 cols 4h..4h+3.  (verified)
// ---------------------------------------------------------------------------
__global__ __launch_bounds__(256) void k0_setup(
    const float* __restrict__ thetas_log, const float* __restrict__ P_param,
    const float* __restrict__ B_param, const float* __restrict__ C,
    const float* __restrict__ gamma_log, float* __restrict__ ws) {
  const int h = blockIdx.x;
  const int tid = threadIdx.x;
  __shared__ float red[4];
  __shared__ float Psh[16];
  __shared__ float nrmsh;

  {
    float4 v = *(const float4*)(B_param + (size_t)h * 1024 + tid * 4);
    float s = v.x * v.x + v.y * v.y + v.z * v.z + v.w * v.w;
#pragma unroll
    for (int off = 32; off > 0; off >>= 1) s += __shfl_down(s, off);
    if ((tid & 63) == 0) red[tid >> 6] = s;
  }
  __syncthreads();

  if (tid == 0) {
    double A[4][4], E[4][4], Tm[4][4];
    for (int i = 0; i < 4; ++i)
      for (int j = 0; j < 4; ++j)
        A[i][j] = (double)P_param[h * 16 + i * 4 + j] - (double)P_param[h * 16 + j * 4 + i];
    double fro = 0.0;
    for (int i = 0; i < 4; ++i) for (int j = 0; j < 4; ++j) fro += A[i][j] * A[i][j];
    fro = sqrt(fro);
    int s = 0;
    while (fro > 0.25 && s < 30) { fro *= 0.5; ++s; }
    double scl = 1.0;
    for (int q2 = 0; q2 < s; ++q2) scl *= 0.5;
    for (int i = 0; i < 4; ++i) for (int j = 0; j < 4; ++j) A[i][j] *= scl;
    for (int i = 0; i < 4; ++i)
      for (int j = 0; j < 4; ++j) { E[i][j] = (i == j) ? 1.0 : 0.0; Tm[i][j] = E[i][j]; }
    for (int k = 1; k <= 16; ++k) {
      double Tn[4][4];
      for (int i = 0; i < 4; ++i)
        for (int j = 0; j < 4; ++j) {
          double acc = 0.0;
          for (int m = 0; m < 4; ++m) acc += Tm[i][m] * A[m][j];
          Tn[i][j] = acc / (double)k;
        }
      for (int i = 0; i < 4; ++i)
        for (int j = 0; j < 4; ++j) { Tm[i][j] = Tn[i][j]; E[i][j] += Tn[i][j]; }
    }
    for (int q2 = 0; q2 < s; ++q2) {
      double E2[4][4];
      for (int i = 0; i < 4; ++i)
        for (int j = 0; j < 4; ++j) {
          double acc = 0.0;
          for (int m = 0; m < 4; ++m) acc += E[i][m] * E[m][j];
          E2[i][j] = acc;
        }
      for (int i = 0; i < 4; ++i) for (int j = 0; j < 4; ++j) E[i][j] = E2[i][j];
    }
    for (int i = 0; i < 4; ++i)
      for (int j = 0; j < 4; ++j) Psh[i * 4 + j] = (float)E[i][j];
  } else if (tid == 64 || tid == 65) {
    const int p = h * 2 + (tid - 64);
    double th = exp((double)thetas_log[p]);
    double g = exp(-exp((double)gamma_log[h]));
    double ar = g * cos(th), ai = g * sin(th);
    float2* Apw = (float2*)(ws + AP_OFF);
    double xr = 1.0, xi = 0.0;
    Apw[p] = make_float2(1.f, 0.f);
    for (int j = 1; j <= LCH; ++j) {
      double nr = xr * ar - xi * ai, ni = xr * ai + xi * ar;
      xr = nr; xi = ni;
      Apw[j * 128 + p] = make_float2((float)xr, (float)xi);
    }
  } else if (tid == 128) {
    double g = exp(-exp((double)gamma_log[h]));
    double tr = (double)red[0] + red[1] + red[2] + red[3];
    nrmsh = (float)sqrt((1.0 - g * g) / tr);
  }
  __syncthreads();

  unsigned short* Mbf = (unsigned short*)(ws + MB_OFF);
  unsigned int*   Cbd = (unsigned int*)(ws + CB_OFF);
  {
    float b0 = B_param[(h * 4 + 0) * 256 + tid];
    float b1 = B_param[(h * 4 + 1) * 256 + tid];
    float b2 = B_param[(h * 4 + 2) * 256 + tid];
    float b3 = B_param[(h * 4 + 3) * 256 + tid];
    float nrm = nrmsh;
#pragma unroll
    for (int N = 0; N < 4; ++N) {
      float acc = Psh[N * 4 + 0] * b0 + Psh[N * 4 + 1] * b1 +
                  Psh[N * 4 + 2] * b2 + Psh[N * 4 + 3] * b3;
      Mbf[(h * 4 + N) * 256 + tid] = (unsigned short)f2bfbits(nrm * acc);
    }
  }
  {
    float4 cv = *(const float4*)(C + (size_t)tid * 256 + h * 4);
    float o[4];
#pragma unroll
    for (int N = 0; N < 4; ++N)
      o[N] = cv.x * Psh[N * 4 + 0] + cv.y * Psh[N * 4 + 1] +
             cv.z * Psh[N * 4 + 2] + cv.w * Psh[N * 4 + 3];
    Cbd[(tid * 256 + h * 4) >> 1]       = pack2(o[0], o[1]);
    Cbd[((tid * 256 + h * 4) >> 1) + 1] = pack2(o[2], o[3]);
  }
}

// ---------------------------------------------------------------------------
// K1: stage u (dword-pair) -> GEMM1 -> scan, direct Zst store.
//     De-aliased LDS: us/wd separate; no barrier between GEMM1 and pack.
// ---------------------------------------------------------------------------
__global__ __launch_bounds__(256, 4) void k1_mfma(
    const float* __restrict__ u, float* __restrict__ ws) {
  __shared__ __align__(16) unsigned short us[LCH * LDK];   // u tile, 16896 B
  __shared__ __align__(16) unsigned int   wd[LCH * LDW];   // W tile,  16896 B

  const int c = blockIdx.x, b = blockIdx.y;
  const int t0 = c * LCH;
  const int tid = threadIdx.x;
  const int L = tid & 63;
  const int w = __builtin_amdgcn_readfirstlane(tid >> 6);
  const int qh = L >> 4, l15 = L & 15;

  // ---- stage u[d][t0+t] -> us[t][j] (j = d/2, pair-packed dwords) ----
  {
    unsigned int* usd = (unsigned int*)us;
    const int dp = tid >> 3;                // 0..31
    const int t4 = (tid & 7) * 4;           // 0..28
#pragma unroll
    for (int i = 0; i < 4; ++i) {
      int j = dp + 32 * i;                  // pair index 0..127
      float4 va = *(const float4*)(u + (size_t)(b * 256 + 2 * j) * TLEN + t0 + t4);
      float4 vb = *(const float4*)(u + (size_t)(b * 256 + 2 * j + 1) * TLEN + t0 + t4);
      float av[4] = {va.x, va.y, va.z, va.w};
      float bv[4] = {vb.x, vb.y, vb.z, vb.w};
#pragma unroll
      for (int dt = 0; dt < 4; ++dt)
        usd[(t4 + dt) * LDW + j] = pack2(av[dt], bv[dt]);
    }
  }
  __syncthreads();

  // ---- GEMM1: W[256][32] = M @ u_tile ----
  f32x4 acc[4][2];
#pragma unroll
  for (int rt = 0; rt < 4; ++rt)
#pragma unroll
    for (int tt = 0; tt < 2; ++tt) acc[rt][tt] = (f32x4){0.f, 0.f, 0.f, 0.f};
  {
    const unsigned short* Mbf = (const unsigned short*)(ws + MB_OFF);
#pragma unroll
    for (int ks = 0; ks < 8; ++ks) {
      short8 af[4], bf[2];
#pragma unroll
      for (int rt = 0; rt < 4; ++rt)
        af[rt] = *(const short8*)(Mbf + (size_t)(w * 64 + rt * 16 + l15) * 256 + ks * 32 + qh * 8);
#pragma unroll
      for (int tt = 0; tt < 2; ++tt)
        bf[tt] = *(const short8*)(us + (tt * 16 + l15) * LDK + ks * 32 + qh * 8);
#pragma unroll
      for (int rt = 0; rt < 4; ++rt)
#pragma unroll
        for (int tt = 0; tt < 2; ++tt)
          acc[rt][tt] = __builtin_amdgcn_mfma_f32_16x16x32_bf16(af[rt], bf[tt], acc[rt][tt], 0, 0, 0);
    }
  }
  // no barrier: wd is separate; each thread packs only its own acc

  // ---- W -> wd[t][p] pair-packed bf16 (D: row=qh*4+q, col=l15) ----
#pragma unroll
  for (int rt = 0; rt < 4; ++rt) {
    int pbase = w * 32 + rt * 8 + qh * 2;   // dword index = state-row/2
#pragma unroll
    for (int tt = 0; tt < 2; ++tt) {
      int t = tt * 16 + l15;
      f32x4 a4 = acc[rt][tt];
      wd[t * LDW + pbase]     = pack2(a4[0], a4[1]);
      wd[t * LDW + pbase + 1] = pack2(a4[2], a4[3]);
    }
  }
  __syncthreads();

  // ---- local scan (fp32 state), z -> Zst DIRECT (coalesced), totals ----
  if (tid < 128) {
    const int p = tid;
    const float2* Apw = (const float2*)(ws + AP_OFF);
    unsigned int* Zg = (unsigned int*)(ws + ZST_OFF) + (size_t)(c * BSZ + b) * 4096;
    float2 a = Apw[128 + p];       // a^1
    float zr = 0.f, zi = 0.f;
#pragma unroll
    for (int t = 0; t < LCH; ++t) {
      unsigned int wv = wd[t * LDW + p];
      float wr = bfbits2f(wv & 0xffffu), wi = bfbits2f(wv >> 16);
      float nr = fmaf(a.x, zr, fmaf(-a.y, zi, wr));
      float ni = fmaf(a.x, zi, fmaf(a.y, zr, wi));
      zr = nr; zi = ni;
      Zg[t * 128 + p] = pack2(zr, zi);     // 128 thr x 4B = 512B coalesced
    }
    ((float2*)(ws + TOT_OFF))[(c * BSZ + b) * 128 + p] = make_float2(zr, zi);
  }
}

// ---------------------------------------------------------------------------
// K2: exclusive scan of Tot over chunks, 16-deep prefetch.
//     Tot[c] := Z_{c-1};  Z_c = Tot_c + a^LCH * Z_{c-1}.
// ---------------------------------------------------------------------------
__global__ __launch_bounds__(128) void k2_carry(float* __restrict__ ws) {
  const int b = blockIdx.x;
  const int p = threadIdx.x;
  const float2* Apw = (const float2*)(ws + AP_OFF);
  float2* Tot = (float2*)(ws + TOT_OFF);
  const float2 aL = Apw[LCH * 128 + p];     // a^LCH
  float cr = 0.f, ci = 0.f;
  for (int c0 = 0; c0 < NCH; c0 += 16) {
    float2 tv[16];
#pragma unroll
    for (int k = 0; k < 16; ++k)
      tv[k] = Tot[(size_t)((c0 + k) * BSZ + b) * 128 + p];   // 16 loads in flight
#pragma unroll
    for (int k = 0; k < 16; ++k) {
      Tot[(size_t)((c0 + k) * BSZ + b) * 128 + p] = make_float2(cr, ci);
      float nr = fmaf(aL.x, cr, fmaf(-aL.y, ci, tv[k].x));
      float ni = fmaf(aL.x, ci, fmaf(aL.y, cr, tv[k].y));
      cr = nr; ci = ni;
    }
  }
}

// ---------------------------------------------------------------------------
// K3: carry = one float2 load; fused reload+correct -> LDS z tile ->
//     MFMA GEMM2 -> out + D⊙u.  (verified round 8)
// ---------------------------------------------------------------------------
__global__ __launch_bounds__(256, 4) void k3_mfma(
    const float* __restrict__ u, const float* __restrict__ Dv,
    const float* __restrict__ ws, float* __restrict__ out) {
  __shared__ __align__(16) unsigned char smem[LCH * LDK * 2];
  unsigned int* wd = (unsigned int*)smem;       // z tile [t][LDW] dwords

  const int c = blockIdx.x, b = blockIdx.y;
  const int t0 = c * LCH;
  const int tid = threadIdx.x;
  const int L = tid & 63;
  const int w = __builtin_amdgcn_readfirstlane(tid >> 6);
  const int qh = L >> 4, l15 = L & 15;

  // ---- fused reload + carry-correct (p constant per thread) ----
  {
    const int p = tid & 127;
    const float2 cv = ((const float2*)(ws + TOT_OFF))[(size_t)(c * BSZ + b) * 128 + p];
    const float2* Apw = (const float2*)(ws + AP_OFF);
    const unsigned int* Zg = (const unsigned int*)(ws + ZST_OFF) + (size_t)(c * BSZ + b) * 4096;
#pragma unroll
    for (int jj = 0; jj < 16; ++jj) {
      int idx = tid + 256 * jj;
      int t = idx >> 7;
      unsigned int wv = Zg[idx];
      float2 ap = Apw[(t + 1) * 128 + p];
      float sr = fmaf(ap.x, cv.x, fmaf(-ap.y, cv.y, bfbits2f(wv & 0xffffu)));
      float si = fmaf(ap.x, cv.y, fmaf(ap.y, cv.x, bfbits2f(wv >> 16)));
      wd[t * LDW + p] = pack2(sr, si);
    }
  }
  __syncthreads();

  // ---- GEMM2: out_tile = C2 @ Z ----
  f32x4 acc[4][2];
#pragma unroll
  for (int rt = 0; rt < 4; ++rt)
#pragma unroll
    for (int tt = 0; tt < 2; ++tt) acc[rt][tt] = (f32x4){0.f, 0.f, 0.f, 0.f};
  {
    const unsigned short* Cbf = (const unsigned short*)(ws + CB_OFF);
    const unsigned short* zs  = (const unsigned short*)smem;
#pragma unroll
    for (int ks = 0; ks < 8; ++ks) {
      short8 af[4], bf[2];
#pragma unroll
      for (int rt = 0; rt < 4; ++rt)
        af[rt] = *(const short8*)(Cbf + (size_t)(w * 64 + rt * 16 + l15) * 256 + ks * 32 + qh * 8);
#pragma unroll
      for (int tt = 0; tt < 2; ++tt)
        bf[tt] = *(const short8*)(zs + (tt * 16 + l15) * LDK + ks * 32 + qh * 8);
#pragma unroll
      for (int rt = 0; rt < 4; ++rt)
#pragma unroll
        for (int tt = 0; tt < 2; ++tt)
          acc[rt][tt] = __builtin_amdgcn_mfma_f32_16x16x32_bf16(af[rt], bf[tt], acc[rt][tt], 0, 0, 0);
    }
  }

  // ---- epilogue: out = acc + D ⊙ u ----
  float dv[4][4];
#pragma unroll
  for (int rt = 0; rt < 4; ++rt)
#pragma unroll
    for (int q = 0; q < 4; ++q) dv[rt][q] = Dv[w * 64 + rt * 16 + qh * 4 + q];
#pragma unroll
  for (int rt = 0; rt < 4; ++rt) {
    int Dbase = w * 64 + rt * 16 + qh * 4;
#pragma unroll
    for (int tt = 0; tt < 2; ++tt) {
      int t = tt * 16 + l15;
      f32x4 a4 = acc[rt][tt];
      size_t obase = (size_t)(b * 256 + Dbase) * TLEN + t0 + t;
#pragma unroll
      for (int q = 0; q < 4; ++q)
        out[obase + (size_t)q * TLEN] = a4[q] + dv[rt][q] * u[obase + (size_t)q * TLEN];
    }
  }
}

extern "C" void kernel_launch(void* const* d_in, const int* in_sizes, int n_in,
                              void* d_out, int out_size, void* d_ws, size_t ws_size,
                              hipStream_t stream) {
  const float* u          = (const float*)d_in[0];
  const float* thetas_log = (const float*)d_in[1];
  const float* P_param    = (const float*)d_in[2];
  const float* B_param    = (const float*)d_in[3];
  const float* C          = (const float*)d_in[4];
  const float* Dvec       = (const float*)d_in[5];
  const float* gamma_log  = (const float*)d_in[6];
  float* out = (float*)d_out;
  float* ws  = (float*)d_ws;

  hipLaunchKernelGGL(k0_setup, dim3(64), dim3(256), 0, stream,
                     thetas_log, P_param, B_param, C, gamma_log, ws);
  hipLaunchKernelGGL(k1_mfma, dim3(NCH, BSZ), dim3(256), 0, stream, u, ws);
  hipLaunchKernelGGL(k2_carry, dim3(BSZ), dim3(128), 0, stream, ws);
  hipLaunchKernelGGL(k3_mfma, dim3(NCH, BSZ), dim3(256), 0, stream, u, Dvec, ws, out);
}

// Round 14
// 156.258 us; speedup vs baseline: 1.6185x; 1.0066x over previous
//
#include <hip/hip_runtime.h>
#include <math.h>

// ---------------------------------------------------------------------------
// RotSSM: out[b,Do,t] = C2 @ scan(M @ u)[.,b,t] + D ⊙ u[b,.,t]
//   Round-13 structure (157.3 µs, ties best) + ONE theme: maximize MLP in
//   the cold-load loops (u is L3-cold every iter — the 268 MB ws re-poison
//   evicts L3). Loads hoisted into registers before dependent LDS writes:
//     k1 staging: 8 f32x4 loads batched (was ~2-deep), then writes.
//     k3 reload: 16 dword Zst loads batched, then correct+write.
//     k3 epilogue: 4 u loads batched before 4 out stores.
//   k0 (64 blocks): trace/expm/norm/Apow + M, C2.
//   k1 (128x8): stage u -> MFMA GEMM1 -> scan -> Zst direct + totals.
//   k2 (8x128): exclusive Tot scan over chunks, 16-deep prefetch.
//   k3 (128x8): carry = one float2 load; reload+correct -> GEMM2 -> out.
// ---------------------------------------------------------------------------

typedef __attribute__((ext_vector_type(8))) short short8;   // 8 bf16 (4 VGPRs)
typedef __attribute__((ext_vector_type(4))) float f32x4;

#define TLEN 4096
#define LCH 32            // chunk length (t per block)
#define NCH 128           // number of chunks
#define BSZ 8
#define LDW 132           // dwords per [t] row (128 + 4 pad)
#define LDK 264           // shorts per [t] row (= LDW*2)

// workspace float offsets (round-8 proven layout)
constexpr int MB_OFF   = 0;                               // M bf16 [256][256]
constexpr int CB_OFF   = 32768;                           // C2 bf16 [256][256]
constexpr int AP_OFF   = 65536;                           // Apow [LCH+1][128] float2
constexpr int ALP_OFF  = AP_OFF + (LCH + 1) * 256;        // (unused, layout keep)
constexpr int TOT_OFF  = ALP_OFF + (NCH + 1) * 256;       // Tot/Carry [NCH][8][128] float2
constexpr int ZST_OFF  = TOT_OFF + NCH * BSZ * 256;       // Zst [NCH*8][4096] dwords

__device__ __forceinline__ float bfbits2f(unsigned int bits16) {
  union { unsigned int u; float f; } v; v.u = bits16 << 16; return v.f;
}
__device__ __forceinline__ unsigned int f2bfbits(float f) {
  union { float f; unsigned int u; } v; v.f = f;
  return (v.u + 0x7fffu + ((v.u >> 16) & 1u)) >> 16;   // RNE, finite inputs
}
__device__ __forceinline__ unsigned int pack2(float x, float y) {
  return f2bfbits(x) | (f2bfbits(y) << 16);
}

// ---------------------------------------------------------------------------
// K0: one block per head. trace -> {expm | Apow | norm, separate waves}
//     -> M rows 4h..4h+3 and C2 cols 4h..4h+3.  (verified)
// ---------------------------------------------------------------------------
__global__ __launch_bounds__(256) void k0_setup(
    const float* __restrict__ thetas_log, const float* __restrict__ P_param,
    const float* __restrict__ B_param, const float* __restrict__ C,
    const float* __restrict__ gamma_log, float* __restrict__ ws) {
  const int h = blockIdx.x;
  const int tid = threadIdx.x;
  __shared__ float red[4];
  __shared__ float Psh[16];
  __shared__ float nrmsh;

  {
    float4 v = *(const float4*)(B_param + (size_t)h * 1024 + tid * 4);
    float s = v.x * v.x + v.y * v.y + v.z * v.z + v.w * v.w;
#pragma unroll
    for (int off = 32; off > 0; off >>= 1) s += __shfl_down(s, off);
    if ((tid & 63) == 0) red[tid >> 6] = s;
  }
  __syncthreads();

  if (tid == 0) {
    double A[4][4], E[4][4], Tm[4][4];
    for (int i = 0; i < 4; ++i)
      for (int j = 0; j < 4; ++j)
        A[i][j] = (double)P_param[h * 16 + i * 4 + j] - (double)P_param[h * 16 + j * 4 + i];
    double fro = 0.0;
    for (int i = 0; i < 4; ++i) for (int j = 0; j < 4; ++j) fro += A[i][j] * A[i][j];
    fro = sqrt(fro);
    int s = 0;
    while (fro > 0.25 && s < 30) { fro *= 0.5; ++s; }
    double scl = 1.0;
    for (int q2 = 0; q2 < s; ++q2) scl *= 0.5;
    for (int i = 0; i < 4; ++i) for (int j = 0; j < 4; ++j) A[i][j] *= scl;
    for (int i = 0; i < 4; ++i)
      for (int j = 0; j < 4; ++j) { E[i][j] = (i == j) ? 1.0 : 0.0; Tm[i][j] = E[i][j]; }
    for (int k = 1; k <= 16; ++k) {
      double Tn[4][4];
      for (int i = 0; i < 4; ++i)
        for (int j = 0; j < 4; ++j) {
          double acc = 0.0;
          for (int m = 0; m < 4; ++m) acc += Tm[i][m] * A[m][j];
          Tn[i][j] = acc / (double)k;
        }
      for (int i = 0; i < 4; ++i)
        for (int j = 0; j < 4; ++j) { Tm[i][j] = Tn[i][j]; E[i][j] += Tn[i][j]; }
    }
    for (int q2 = 0; q2 < s; ++q2) {
      double E2[4][4];
      for (int i = 0; i < 4; ++i)
        for (int j = 0; j < 4; ++j) {
          double acc = 0.0;
          for (int m = 0; m < 4; ++m) acc += E[i][m] * E[m][j];
          E2[i][j] = acc;
        }
      for (int i = 0; i < 4; ++i) for (int j = 0; j < 4; ++j) E[i][j] = E2[i][j];
    }
    for (int i = 0; i < 4; ++i)
      for (int j = 0; j < 4; ++j) Psh[i * 4 + j] = (float)E[i][j];
  } else if (tid == 64 || tid == 65) {
    const int p = h * 2 + (tid - 64);
    double th = exp((double)thetas_log[p]);
    double g = exp(-exp((double)gamma_log[h]));
    double ar = g * cos(th), ai = g * sin(th);
    float2* Apw = (float2*)(ws + AP_OFF);
    double xr = 1.0, xi = 0.0;
    Apw[p] = make_float2(1.f, 0.f);
    for (int j = 1; j <= LCH; ++j) {
      double nr = xr * ar - xi * ai, ni = xr * ai + xi * ar;
      xr = nr; xi = ni;
      Apw[j * 128 + p] = make_float2((float)xr, (float)xi);
    }
  } else if (tid == 128) {
    double g = exp(-exp((double)gamma_log[h]));
    double tr = (double)red[0] + red[1] + red[2] + red[3];
    nrmsh = (float)sqrt((1.0 - g * g) / tr);
  }
  __syncthreads();

  unsigned short* Mbf = (unsigned short*)(ws + MB_OFF);
  unsigned int*   Cbd = (unsigned int*)(ws + CB_OFF);
  {
    float b0 = B_param[(h * 4 + 0) * 256 + tid];
    float b1 = B_param[(h * 4 + 1) * 256 + tid];
    float b2 = B_param[(h * 4 + 2) * 256 + tid];
    float b3 = B_param[(h * 4 + 3) * 256 + tid];
    float nrm = nrmsh;
#pragma unroll
    for (int N = 0; N < 4; ++N) {
      float acc = Psh[N * 4 + 0] * b0 + Psh[N * 4 + 1] * b1 +
                  Psh[N * 4 + 2] * b2 + Psh[N * 4 + 3] * b3;
      Mbf[(h * 4 + N) * 256 + tid] = (unsigned short)f2bfbits(nrm * acc);
    }
  }
  {
    float4 cv = *(const float4*)(C + (size_t)tid * 256 + h * 4);
    float o[4];
#pragma unroll
    for (int N = 0; N < 4; ++N)
      o[N] = cv.x * Psh[N * 4 + 0] + cv.y * Psh[N * 4 + 1] +
             cv.z * Psh[N * 4 + 2] + cv.w * Psh[N * 4 + 3];
    Cbd[(tid * 256 + h * 4) >> 1]       = pack2(o[0], o[1]);
    Cbd[((tid * 256 + h * 4) >> 1) + 1] = pack2(o[2], o[3]);
  }
}

// ---------------------------------------------------------------------------
// K1: stage u (8-deep batched loads) -> GEMM1 -> scan, direct Zst store.
//     De-aliased LDS (us/wd separate; no GEMM1->pack barrier).
// ---------------------------------------------------------------------------
__global__ __launch_bounds__(256, 4) void k1_mfma(
    const float* __restrict__ u, float* __restrict__ ws) {
  __shared__ __align__(16) unsigned short us[LCH * LDK];   // u tile, 16896 B
  __shared__ __align__(16) unsigned int   wd[LCH * LDW];   // W tile,  16896 B

  const int c = blockIdx.x, b = blockIdx.y;
  const int t0 = c * LCH;
  const int tid = threadIdx.x;
  const int L = tid & 63;
  const int w = __builtin_amdgcn_readfirstlane(tid >> 6);
  const int qh = L >> 4, l15 = L & 15;

  // ---- stage u: ALL 8 loads issued first (8-deep MLP), then LDS writes ----
  {
    unsigned int* usd = (unsigned int*)us;
    const int dp = tid >> 3;                // 0..31
    const int t4 = (tid & 7) * 4;           // 0..28
    f32x4 va[4], vb[4];
#pragma unroll
    for (int i = 0; i < 4; ++i) {
      int j = dp + 32 * i;                  // pair index 0..127
      va[i] = *(const f32x4*)(u + (size_t)(b * 256 + 2 * j) * TLEN + t0 + t4);
      vb[i] = *(const f32x4*)(u + (size_t)(b * 256 + 2 * j + 1) * TLEN + t0 + t4);
    }
#pragma unroll
    for (int i = 0; i < 4; ++i) {
      int j = dp + 32 * i;
#pragma unroll
      for (int dt = 0; dt < 4; ++dt)
        usd[(t4 + dt) * LDW + j] = pack2(va[i][dt], vb[i][dt]);
    }
  }
  __syncthreads();

  // ---- GEMM1: W[256][32] = M @ u_tile ----
  f32x4 acc[4][2];
#pragma unroll
  for (int rt = 0; rt < 4; ++rt)
#pragma unroll
    for (int tt = 0; tt < 2; ++tt) acc[rt][tt] = (f32x4){0.f, 0.f, 0.f, 0.f};
  {
    const unsigned short* Mbf = (const unsigned short*)(ws + MB_OFF);
#pragma unroll
    for (int ks = 0; ks < 8; ++ks) {
      short8 af[4], bf[2];
#pragma unroll
      for (int rt = 0; rt < 4; ++rt)
        af[rt] = *(const short8*)(Mbf + (size_t)(w * 64 + rt * 16 + l15) * 256 + ks * 32 + qh * 8);
#pragma unroll
      for (int tt = 0; tt < 2; ++tt)
        bf[tt] = *(const short8*)(us + (tt * 16 + l15) * LDK + ks * 32 + qh * 8);
#pragma unroll
      for (int rt = 0; rt < 4; ++rt)
#pragma unroll
        for (int tt = 0; tt < 2; ++tt)
          acc[rt][tt] = __builtin_amdgcn_mfma_f32_16x16x32_bf16(af[rt], bf[tt], acc[rt][tt], 0, 0, 0);
    }
  }
  // no barrier: wd is separate; each thread packs only its own acc

  // ---- W -> wd[t][p] pair-packed bf16 (D: row=qh*4+q, col=l15) ----
#pragma unroll
  for (int rt = 0; rt < 4; ++rt) {
    int pbase = w * 32 + rt * 8 + qh * 2;   // dword index = state-row/2
#pragma unroll
    for (int tt = 0; tt < 2; ++tt) {
      int t = tt * 16 + l15;
      f32x4 a4 = acc[rt][tt];
      wd[t * LDW + pbase]     = pack2(a4[0], a4[1]);
      wd[t * LDW + pbase + 1] = pack2(a4[2], a4[3]);
    }
  }
  __syncthreads();

  // ---- local scan (fp32 state), z -> Zst DIRECT (coalesced), totals ----
  if (tid < 128) {
    const int p = tid;
    const float2* Apw = (const float2*)(ws + AP_OFF);
    unsigned int* Zg = (unsigned int*)(ws + ZST_OFF) + (size_t)(c * BSZ + b) * 4096;
    float2 a = Apw[128 + p];       // a^1
    float zr = 0.f, zi = 0.f;
#pragma unroll
    for (int t = 0; t < LCH; ++t) {
      unsigned int wv = wd[t * LDW + p];
      float wr = bfbits2f(wv & 0xffffu), wi = bfbits2f(wv >> 16);
      float nr = fmaf(a.x, zr, fmaf(-a.y, zi, wr));
      float ni = fmaf(a.x, zi, fmaf(a.y, zr, wi));
      zr = nr; zi = ni;
      Zg[t * 128 + p] = pack2(zr, zi);     // 128 thr x 4B = 512B coalesced
    }
    ((float2*)(ws + TOT_OFF))[(c * BSZ + b) * 128 + p] = make_float2(zr, zi);
  }
}

// ---------------------------------------------------------------------------
// K2: exclusive scan of Tot over chunks, 16-deep prefetch.
//     Tot[c] := Z_{c-1};  Z_c = Tot_c + a^LCH * Z_{c-1}.
// ---------------------------------------------------------------------------
__global__ __launch_bounds__(128) void k2_carry(float* __restrict__ ws) {
  const int b = blockIdx.x;
  const int p = threadIdx.x;
  const float2* Apw = (const float2*)(ws + AP_OFF);
  float2* Tot = (float2*)(ws + TOT_OFF);
  const float2 aL = Apw[LCH * 128 + p];     // a^LCH
  float cr = 0.f, ci = 0.f;
  for (int c0 = 0; c0 < NCH; c0 += 16) {
    float2 tv[16];
#pragma unroll
    for (int k = 0; k < 16; ++k)
      tv[k] = Tot[(size_t)((c0 + k) * BSZ + b) * 128 + p];   // 16 loads in flight
#pragma unroll
    for (int k = 0; k < 16; ++k) {
      Tot[(size_t)((c0 + k) * BSZ + b) * 128 + p] = make_float2(cr, ci);
      float nr = fmaf(aL.x, cr, fmaf(-aL.y, ci, tv[k].x));
      float ni = fmaf(aL.x, ci, fmaf(aL.y, cr, tv[k].y));
      cr = nr; ci = ni;
    }
  }
}

// ---------------------------------------------------------------------------
// K3: carry = one float2 load; reload (16-deep batched) + correct ->
//     LDS z tile -> MFMA GEMM2 -> out + D⊙u (batched u loads).
// ---------------------------------------------------------------------------
__global__ __launch_bounds__(256, 4) void k3_mfma(
    const float* __restrict__ u, const float* __restrict__ Dv,
    const float* __restrict__ ws, float* __restrict__ out) {
  __shared__ __align__(16) unsigned char smem[LCH * LDK * 2];
  unsigned int* wd = (unsigned int*)smem;       // z tile [t][LDW] dwords

  const int c = blockIdx.x, b = blockIdx.y;
  const int t0 = c * LCH;
  const int tid = threadIdx.x;
  const int L = tid & 63;
  const int w = __builtin_amdgcn_readfirstlane(tid >> 6);
  const int qh = L >> 4, l15 = L & 15;

  // ---- reload: ALL 16 Zst loads first (16-deep MLP), then correct+write ----
  {
    const int p = tid & 127;
    const float2 cv = ((const float2*)(ws + TOT_OFF))[(size_t)(c * BSZ + b) * 128 + p];
    const float2* Apw = (const float2*)(ws + AP_OFF);
    const unsigned int* Zg = (const unsigned int*)(ws + ZST_OFF) + (size_t)(c * BSZ + b) * 4096;
    unsigned int zv[16];
#pragma unroll
    for (int jj = 0; jj < 16; ++jj)
      zv[jj] = Zg[tid + 256 * jj];
#pragma unroll
    for (int jj = 0; jj < 16; ++jj) {
      int t = (tid + 256 * jj) >> 7;
      float2 ap = Apw[(t + 1) * 128 + p];
      float sr = fmaf(ap.x, cv.x, fmaf(-ap.y, cv.y, bfbits2f(zv[jj] & 0xffffu)));
      float si = fmaf(ap.x, cv.y, fmaf(ap.y, cv.x, bfbits2f(zv[jj] >> 16)));
      wd[t * LDW + p] = pack2(sr, si);
    }
  }
  __syncthreads();

  // ---- GEMM2: out_tile = C2 @ Z ----
  f32x4 acc[4][2];
#pragma unroll
  for (int rt = 0; rt < 4; ++rt)
#pragma unroll
    for (int tt = 0; tt < 2; ++tt) acc[rt][tt] = (f32x4){0.f, 0.f, 0.f, 0.f};
  {
    const unsigned short* Cbf = (const unsigned short*)(ws + CB_OFF);
    const unsigned short* zs  = (const unsigned short*)smem;
#pragma unroll
    for (int ks = 0; ks < 8; ++ks) {
      short8 af[4], bf[2];
#pragma unroll
      for (int rt = 0; rt < 4; ++rt)
        af[rt] = *(const short8*)(Cbf + (size_t)(w * 64 + rt * 16 + l15) * 256 + ks * 32 + qh * 8);
#pragma unroll
      for (int tt = 0; tt < 2; ++tt)
        bf[tt] = *(const short8*)(zs + (tt * 16 + l15) * LDK + ks * 32 + qh * 8);
#pragma unroll
      for (int rt = 0; rt < 4; ++rt)
#pragma unroll
        for (int tt = 0; tt < 2; ++tt)
          acc[rt][tt] = __builtin_amdgcn_mfma_f32_16x16x32_bf16(af[rt], bf[tt], acc[rt][tt], 0, 0, 0);
    }
  }

  // ---- epilogue: out = acc + D ⊙ u (u loads batched per sub-tile) ----
  float dv[4][4];
#pragma unroll
  for (int rt = 0; rt < 4; ++rt)
#pragma unroll
    for (int q = 0; q < 4; ++q) dv[rt][q] = Dv[w * 64 + rt * 16 + qh * 4 + q];
#pragma unroll
  for (int rt = 0; rt < 4; ++rt) {
    int Dbase = w * 64 + rt * 16 + qh * 4;
#pragma unroll
    for (int tt = 0; tt < 2; ++tt) {
      int t = tt * 16 + l15;
      f32x4 a4 = acc[rt][tt];
      size_t obase = (size_t)(b * 256 + Dbase) * TLEN + t0 + t;
      float uv[4];
#pragma unroll
      for (int q = 0; q < 4; ++q)
        uv[q] = u[obase + (size_t)q * TLEN];
#pragma unroll
      for (int q = 0; q < 4; ++q)
        out[obase + (size_t)q * TLEN] = a4[q] + dv[rt][q] * uv[q];
    }
  }
}

extern "C" void kernel_launch(void* const* d_in, const int* in_sizes, int n_in,
                              void* d_out, int out_size, void* d_ws, size_t ws_size,
                              hipStream_t stream) {
  const float* u          = (const float*)d_in[0];
  const float* thetas_log = (const float*)d_in[1];
  const float* P_param    = (const float*)d_in[2];
  const float* B_param    = (const float*)d_in[3];
  const float* C          = (const float*)d_in[4];
  const float* Dvec       = (const float*)d_in[5];
  const float* gamma_log  = (const float*)d_in[6];
  float* out = (float*)d_out;
  float* ws  = (float*)d_ws;

  hipLaunchKernelGGL(k0_setup, dim3(64), dim3(256), 0, stream,
                     thetas_log, P_param, B_param, C, gamma_log, ws);
  hipLaunchKernelGGL(k1_mfma, dim3(NCH, BSZ), dim3(256), 0, stream, u, ws);
  hipLaunchKernelGGL(k2_carry, dim3(BSZ), dim3(128), 0, stream, ws);
  hipLaunchKernelGGL(k3_mfma, dim3(NCH, BSZ), dim3(256), 0, stream, u, Dvec, ws, out);
}